// Round 3
// baseline (18946.384 us; speedup 1.0000x reference)
//
#include <hip/hip_runtime.h>
#include <hip/hip_bf16.h>

// 3D Swin: grid (Dg,Hg,Wg)=(32,64,64), L=131072 tokens, C=64, WIN=4 (N=64),
// 2 heads x 32, shift=2 on odd layers, FFN hidden 128, 16 layers.

#define DG 32
#define HGRID 64
#define WGRID 64
#define L_TOK (DG*HGRID*WGRID)   // 131072
#define EPSV 1.1920929e-07f

// ---------------------------------------------------------------- patch embed
__global__ __launch_bounds__(256) void k_embed(const float* __restrict__ x,
        const float* __restrict__ up_w, const float* __restrict__ up_b,
        float* __restrict__ h) {
    int t = blockIdx.x * 256 + threadIdx.x;       // L*4 threads
    int tok = t >> 2, seg = t & 3;
    int xg = tok & 63, yg = (tok >> 6) & 63, zg = tok >> 12;
    const float* xp = x + ((size_t)(zg * 2) * 256 + yg * 4) * 256 + xg * 4;
    float p[32];
    #pragma unroll
    for (int dz = 0; dz < 2; ++dz)
        #pragma unroll
        for (int dy = 0; dy < 4; ++dy) {
            float4 v = *reinterpret_cast<const float4*>(xp + ((size_t)dz * 256 + dy) * 256);
            int b = (dz * 4 + dy) * 4;
            p[b] = v.x; p[b + 1] = v.y; p[b + 2] = v.z; p[b + 3] = v.w;
        }
    float acc[16];
    #pragma unroll
    for (int j = 0; j < 16; ++j) acc[j] = up_b[seg * 16 + j];
    #pragma unroll
    for (int k = 0; k < 32; ++k) {
        float a = p[k];
        const float* wr = up_w + k * 64 + seg * 16;
        #pragma unroll
        for (int j = 0; j < 16; ++j) acc[j] = fmaf(a, wr[j], acc[j]);
    }
    float* op = h + (size_t)tok * 64 + seg * 16;
    #pragma unroll
    for (int j = 0; j < 16; ++j) op[j] = acc[j];
}

// ------------------------------------------------- fused window attention layer
// block = 256 threads = one 64-token window. In-place residual update of h.
template <int SHIFTED>
__global__ __launch_bounds__(256) void k_attn(float* __restrict__ h,
        const float* __restrict__ ln1, const float* __restrict__ qkvw,
        const float* __restrict__ projw, const float* __restrict__ projb) {
    __shared__ float hn[64][65];       // normalized tokens, later attn output
    __shared__ float qkv_s[64][193];   // q[0:64) k[64:128) v[128:192)
    __shared__ int rid_s[64];
    __shared__ int lidx_s[64];

    int w = blockIdx.x;
    int wx = w & 15, wy = (w >> 4) & 15, wz = w >> 8;
    int tid = threadIdx.x;
    int tok = tid >> 2, seg = tid & 3;

    // ---- phase A: gather (with shift-roll), RMSNorm, stage to LDS
    {
        int nz = tok >> 4, ny = (tok >> 2) & 3, nx = tok & 3;
        int gz = wz * 4 + nz, gy = wy * 4 + ny, gx = wx * 4 + nx;
        int sz, sy, sx;
        if (SHIFTED) { sz = (gz + 2) & 31; sy = (gy + 2) & 63; sx = (gx + 2) & 63; }
        else         { sz = gz; sy = gy; sx = gx; }
        int l = (sz * 64 + sy) * 64 + sx;
        if (seg == 0) {
            lidx_s[tok] = l;
            if (SHIFTED) {
                int rz = gz >= 30 ? 2 : (gz >= 28 ? 1 : 0);
                int ry = gy >= 62 ? 2 : (gy >= 60 ? 1 : 0);
                int rx = gx >= 62 ? 2 : (gx >= 60 ? 1 : 0);
                rid_s[tok] = rz * 9 + ry * 3 + rx;
            }
        }
        const float* hp = h + (size_t)l * 64 + seg * 16;
        float v[16];
        #pragma unroll
        for (int j4 = 0; j4 < 4; ++j4) {
            float4 t4 = *reinterpret_cast<const float4*>(hp + j4 * 4);
            v[j4 * 4] = t4.x; v[j4 * 4 + 1] = t4.y; v[j4 * 4 + 2] = t4.z; v[j4 * 4 + 3] = t4.w;
        }
        float ss = 0.f;
        #pragma unroll
        for (int j = 0; j < 16; ++j) ss = fmaf(v[j], v[j], ss);
        ss += __shfl_xor(ss, 1);
        ss += __shfl_xor(ss, 2);
        float r = rsqrtf(ss * (1.0f / 64.0f) + EPSV);
        #pragma unroll
        for (int j = 0; j < 16; ++j) hn[tok][seg * 16 + j] = v[j] * r * ln1[seg * 16 + j];
    }
    __syncthreads();

    // ---- phase B: qkv = hn @ qkv_w   (each thread: 1 token x 48 out channels)
    {
        float acc[48];
        #pragma unroll
        for (int j = 0; j < 48; ++j) acc[j] = 0.f;
        const float* wq = qkvw + seg * 48;
        #pragma unroll 4
        for (int k = 0; k < 64; ++k) {
            float a = hn[tok][k];
            const float* wr = wq + k * 192;
            #pragma unroll
            for (int j = 0; j < 48; ++j) acc[j] = fmaf(a, wr[j], acc[j]);
        }
        #pragma unroll
        for (int j = 0; j < 48; ++j) qkv_s[tok][seg * 48 + j] = acc[j];
    }
    __syncthreads();

    // ---- phase C: attention. 128 threads: (head hh, row n)
    if (tid < 128) {
        int hh = tid >> 6, n = tid & 63;
        float q[32];
        #pragma unroll
        for (int d = 0; d < 32; ++d) q[d] = qkv_s[n][hh * 32 + d];
        float s[64];
        const float scale = 0.17677669529663687f;  // 32^-0.5
        int myrid = SHIFTED ? rid_s[n] : 0;
        #pragma unroll
        for (int m = 0; m < 64; ++m) {
            float a = 0.f;
            #pragma unroll
            for (int d = 0; d < 32; ++d) a = fmaf(q[d], qkv_s[m][64 + hh * 32 + d], a);
            a *= scale;
            if (SHIFTED && rid_s[m] != myrid) a -= 100.f;
            s[m] = a;
        }
        float mx = s[0];
        #pragma unroll
        for (int m = 1; m < 64; ++m) mx = fmaxf(mx, s[m]);
        float sum = 0.f;
        #pragma unroll
        for (int m = 0; m < 64; ++m) { float e = __expf(s[m] - mx); s[m] = e; sum += e; }
        float inv = 1.0f / sum;
        float o[32];
        #pragma unroll
        for (int d = 0; d < 32; ++d) o[d] = 0.f;
        #pragma unroll
        for (int m = 0; m < 64; ++m) {
            float p = s[m];
            #pragma unroll
            for (int d = 0; d < 32; ++d) o[d] = fmaf(p, qkv_s[m][128 + hh * 32 + d], o[d]);
        }
        #pragma unroll
        for (int d = 0; d < 32; ++d) hn[n][hh * 32 + d] = o[d] * inv;
    }
    __syncthreads();

    // ---- phase D: proj + bias + residual (in place)
    {
        float acc[16];
        const float* pb = projb + seg * 16;
        #pragma unroll
        for (int j = 0; j < 16; ++j) acc[j] = pb[j];
        #pragma unroll 4
        for (int k = 0; k < 64; ++k) {
            float a = hn[tok][k];
            const float* wr = projw + k * 64 + seg * 16;
            #pragma unroll
            for (int j = 0; j < 16; ++j) acc[j] = fmaf(a, wr[j], acc[j]);
        }
        int l = lidx_s[tok];
        float* op = h + (size_t)l * 64 + seg * 16;
        #pragma unroll
        for (int j4 = 0; j4 < 4; ++j4) {
            float4 t4 = *reinterpret_cast<const float4*>(op + j4 * 4);
            t4.x += acc[j4 * 4]; t4.y += acc[j4 * 4 + 1];
            t4.z += acc[j4 * 4 + 2]; t4.w += acc[j4 * 4 + 3];
            *reinterpret_cast<float4*>(op + j4 * 4) = t4;
        }
    }
}

// ------------------------------------------------------------- fused MLP layer
__global__ __launch_bounds__(256) void k_mlp(float* __restrict__ h,
        const float* __restrict__ ln2, const float* __restrict__ w1,
        const float* __restrict__ b1, const float* __restrict__ w2,
        const float* __restrict__ b2) {
    __shared__ float xt[64][65];
    __shared__ float ht[64][130];
    int tid = threadIdx.x;
    int tok = tid >> 2, seg = tid & 3;
    size_t gtok = (size_t)blockIdx.x * 64 + tok;

    // rmsnorm
    {
        const float* hp = h + gtok * 64 + seg * 16;
        float v[16];
        #pragma unroll
        for (int j4 = 0; j4 < 4; ++j4) {
            float4 t4 = *reinterpret_cast<const float4*>(hp + j4 * 4);
            v[j4 * 4] = t4.x; v[j4 * 4 + 1] = t4.y; v[j4 * 4 + 2] = t4.z; v[j4 * 4 + 3] = t4.w;
        }
        float ss = 0.f;
        #pragma unroll
        for (int j = 0; j < 16; ++j) ss = fmaf(v[j], v[j], ss);
        ss += __shfl_xor(ss, 1);
        ss += __shfl_xor(ss, 2);
        float r = rsqrtf(ss * (1.0f / 64.0f) + EPSV);
        #pragma unroll
        for (int j = 0; j < 16; ++j) xt[tok][seg * 16 + j] = v[j] * r * ln2[seg * 16 + j];
    }
    __syncthreads();

    // hidden = gelu(xt @ w1 + b1)   (thread: 1 token x 32 hidden)
    {
        float acc[32];
        #pragma unroll
        for (int j = 0; j < 32; ++j) acc[j] = b1[seg * 32 + j];
        #pragma unroll 4
        for (int k = 0; k < 64; ++k) {
            float a = xt[tok][k];
            const float* wr = w1 + k * 128 + seg * 32;
            #pragma unroll
            for (int j = 0; j < 32; ++j) acc[j] = fmaf(a, wr[j], acc[j]);
        }
        #pragma unroll
        for (int j = 0; j < 32; ++j) {
            float u = acc[j];
            ht[tok][seg * 32 + j] = 0.5f * u * (1.0f + erff(u * 0.70710678118654752f));
        }
    }
    __syncthreads();

    // out = ht @ w2 + b2 + residual
    {
        float acc[16];
        #pragma unroll
        for (int j = 0; j < 16; ++j) acc[j] = b2[seg * 16 + j];
        #pragma unroll 4
        for (int k = 0; k < 128; ++k) {
            float a = ht[tok][k];
            const float* wr = w2 + k * 64 + seg * 16;
            #pragma unroll
            for (int j = 0; j < 16; ++j) acc[j] = fmaf(a, wr[j], acc[j]);
        }
        float* op = h + gtok * 64 + seg * 16;
        #pragma unroll
        for (int j4 = 0; j4 < 4; ++j4) {
            float4 t4 = *reinterpret_cast<const float4*>(op + j4 * 4);
            t4.x += acc[j4 * 4]; t4.y += acc[j4 * 4 + 1];
            t4.z += acc[j4 * 4 + 2]; t4.w += acc[j4 * 4 + 3];
            *reinterpret_cast<float4*>(op + j4 * 4) = t4;
        }
    }
}

// --------------------------------------------------------------- down + fold
__global__ __launch_bounds__(256) void k_down(const float* __restrict__ h,
        const float* __restrict__ wp, const float* __restrict__ bp,
        const float* __restrict__ wc, const float* __restrict__ bc,
        float* __restrict__ out) {
    int t = blockIdx.x * 256 + threadIdx.x;   // L*2 threads
    int tok = t >> 1, pc = t & 1;
    const float* wsel = pc ? wc : wp;
    const float* bsel = pc ? bc : bp;
    float* obase = out + (size_t)pc * (64u * 256u * 256u);
    float hv[64];
    const float* hp = h + (size_t)tok * 64;
    #pragma unroll
    for (int j4 = 0; j4 < 16; ++j4) {
        float4 t4 = *reinterpret_cast<const float4*>(hp + j4 * 4);
        hv[j4 * 4] = t4.x; hv[j4 * 4 + 1] = t4.y; hv[j4 * 4 + 2] = t4.z; hv[j4 * 4 + 3] = t4.w;
    }
    float acc[32];
    #pragma unroll
    for (int j = 0; j < 32; ++j) acc[j] = bsel[j];
    #pragma unroll 4
    for (int k = 0; k < 64; ++k) {
        float a = hv[k];
        const float* wr = wsel + k * 32;
        #pragma unroll
        for (int j = 0; j < 32; ++j) acc[j] = fmaf(a, wr[j], acc[j]);
    }
    int xg = tok & 63, yg = (tok >> 6) & 63, zg = tok >> 12;
    float* op = obase + ((size_t)(zg * 2) * 256 + yg * 4) * 256 + xg * 4;
    #pragma unroll
    for (int dz = 0; dz < 2; ++dz)
        #pragma unroll
        for (int dy = 0; dy < 4; ++dy) {
            int b = (dz * 4 + dy) * 4;
            *reinterpret_cast<float4*>(op + ((size_t)dz * 256 + dy) * 256) =
                make_float4(acc[b], acc[b + 1], acc[b + 2], acc[b + 3]);
        }
}

// --------------------------------------------------------------------- launch
extern "C" void kernel_launch(void* const* d_in, const int* in_sizes, int n_in,
                              void* d_out, int out_size, void* d_ws, size_t ws_size,
                              hipStream_t stream) {
    const float* x        = (const float*)d_in[0];
    const float* up_w     = (const float*)d_in[1];
    const float* up_b     = (const float*)d_in[2];
    const float* ln1_w    = (const float*)d_in[3];
    const float* qkv_w    = (const float*)d_in[4];
    const float* proj_w   = (const float*)d_in[5];
    const float* proj_b   = (const float*)d_in[6];
    const float* ln2_w    = (const float*)d_in[7];
    const float* mlp_w1   = (const float*)d_in[8];
    const float* mlp_b1   = (const float*)d_in[9];
    const float* mlp_w2   = (const float*)d_in[10];
    const float* mlp_b2   = (const float*)d_in[11];
    const float* down_p_w = (const float*)d_in[12];
    const float* down_p_b = (const float*)d_in[13];
    const float* down_c_w = (const float*)d_in[14];
    const float* down_c_b = (const float*)d_in[15];
    float* out = (float*)d_out;
    float* h   = (float*)d_ws;   // L_TOK * 64 floats = 32 MB

    k_embed<<<2048, 256, 0, stream>>>(x, up_w, up_b, h);
    for (int i = 0; i < 16; ++i) {
        const float* ln1 = ln1_w + i * 64;
        const float* qw  = qkv_w  + (size_t)i * 64 * 192;
        const float* pw  = proj_w + (size_t)i * 64 * 64;
        const float* pb  = proj_b + i * 64;
        if (i & 1) k_attn<1><<<2048, 256, 0, stream>>>(h, ln1, qw, pw, pb);
        else       k_attn<0><<<2048, 256, 0, stream>>>(h, ln1, qw, pw, pb);
        k_mlp<<<2048, 256, 0, stream>>>(h, ln2_w + i * 64,
                mlp_w1 + (size_t)i * 64 * 128, mlp_b1 + i * 128,
                mlp_w2 + (size_t)i * 128 * 64, mlp_b2 + i * 64);
    }
    k_down<<<1024, 256, 0, stream>>>(h, down_p_w, down_p_b, down_c_w, down_c_b, out);
}

// Round 5
// 3551.743 us; speedup vs baseline: 5.3344x; 5.3344x over previous
//
#include <hip/hip_runtime.h>
#include <hip/hip_bf16.h>

// 3D Swin: grid (32,64,64), L=131072, C=64, WIN=4 (N=64), 2 heads x 32,
// shift=2 odd layers, FFN 128, 16 layers. Fully fused per-layer kernel.

#define EPSV 1.1920929e-07f

// ---------------------------------------------------------------- patch embed
__global__ __launch_bounds__(256) void k_embed(const float* __restrict__ x,
        const float* __restrict__ up_w, const float* __restrict__ up_b,
        float* __restrict__ h) {
    int t = blockIdx.x * 256 + threadIdx.x;       // L*4 threads
    int tok = t >> 2, seg = t & 3;
    int xg = tok & 63, yg = (tok >> 6) & 63, zg = tok >> 12;
    const float* xp = x + ((size_t)(zg * 2) * 256 + yg * 4) * 256 + xg * 4;
    float p[32];
    #pragma unroll
    for (int dz = 0; dz < 2; ++dz)
        #pragma unroll
        for (int dy = 0; dy < 4; ++dy) {
            float4 v = *reinterpret_cast<const float4*>(xp + ((size_t)dz * 256 + dy) * 256);
            int b = (dz * 4 + dy) * 4;
            p[b] = v.x; p[b + 1] = v.y; p[b + 2] = v.z; p[b + 3] = v.w;
        }
    float acc[16];
    #pragma unroll
    for (int j = 0; j < 16; ++j) acc[j] = up_b[seg * 16 + j];
    #pragma unroll
    for (int k = 0; k < 32; ++k) {
        float a = p[k];
        const float* wr = up_w + k * 64 + seg * 16;
        #pragma unroll
        for (int j = 0; j < 16; ++j) acc[j] = fmaf(a, wr[j], acc[j]);
    }
    float* op = h + (size_t)tok * 64 + seg * 16;
    #pragma unroll
    for (int j = 0; j < 16; ++j) op[j] = acc[j];
}

// -------------------------------------------------------- fused full layer
// block = 256 threads = one 64-token window. One h read, one h write.
template <int SHIFTED>
__global__ __launch_bounds__(256, 2) void k_layer(float* __restrict__ h,
        const float* __restrict__ ln1, const float* __restrict__ qkvw,
        const float* __restrict__ projw, const float* __restrict__ projb,
        const float* __restrict__ ln2, const float* __restrict__ w1,
        const float* __restrict__ b1, const float* __restrict__ w2,
        const float* __restrict__ b2) {
    __shared__ float hn[64][68];    // norm1 -> attn-out -> xt -> mlp2-out
    __shared__ float qs[64][196];   // qkv -> proj-out -> ht (mlp hidden)
    __shared__ int rid_s[64];

    int w = blockIdx.x;
    int wx = w & 15, wy = (w >> 4) & 15, wz = w >> 8;
    int tid = threadIdx.x;
    int tok = tid >> 2, seg = tid & 3;
    int jg = tid & 15, tg = tid >> 4;   // GEMM-phase tiling: 16 ch-groups x 16 tok-groups

    float v[16];        // this thread's (tok,seg) residual slice; becomes r2
    int lidx;

    // ---- A: gather (shift-roll), RMSNorm(ln1) -> hn
    {
        int nz = tok >> 4, ny = (tok >> 2) & 3, nx = tok & 3;
        int gz = wz * 4 + nz, gy = wy * 4 + ny, gx = wx * 4 + nx;
        int sz, sy, sx;
        if (SHIFTED) { sz = (gz + 2) & 31; sy = (gy + 2) & 63; sx = (gx + 2) & 63; }
        else         { sz = gz; sy = gy; sx = gx; }
        lidx = (sz * 64 + sy) * 64 + sx;
        if (SHIFTED && seg == 0) {
            int rz = gz >= 30 ? 2 : (gz >= 28 ? 1 : 0);
            int ry = gy >= 62 ? 2 : (gy >= 60 ? 1 : 0);
            int rx = gx >= 62 ? 2 : (gx >= 60 ? 1 : 0);
            rid_s[tok] = rz * 9 + ry * 3 + rx;
        }
        const float* hp = h + (size_t)lidx * 64 + seg * 16;
        #pragma unroll
        for (int c = 0; c < 4; ++c) {
            float4 t4 = *reinterpret_cast<const float4*>(hp + c * 4);
            v[c * 4] = t4.x; v[c * 4 + 1] = t4.y; v[c * 4 + 2] = t4.z; v[c * 4 + 3] = t4.w;
        }
        float ss = 0.f;
        #pragma unroll
        for (int j = 0; j < 16; ++j) ss = fmaf(v[j], v[j], ss);
        ss += __shfl_xor(ss, 1);
        ss += __shfl_xor(ss, 2);
        float r = rsqrtf(ss * (1.0f / 64.0f) + EPSV);
        #pragma unroll
        for (int c = 0; c < 4; ++c) {
            float4 o4;
            o4.x = v[c * 4 + 0] * r * ln1[seg * 16 + c * 4 + 0];
            o4.y = v[c * 4 + 1] * r * ln1[seg * 16 + c * 4 + 1];
            o4.z = v[c * 4 + 2] * r * ln1[seg * 16 + c * 4 + 2];
            o4.w = v[c * 4 + 3] * r * ln1[seg * 16 + c * 4 + 3];
            *reinterpret_cast<float4*>(&hn[tok][seg * 16 + c * 4]) = o4;
        }
    }
    __syncthreads();

    // ---- B: qkv GEMM. thread = (jg: 12 out-ch, tg: 4 tokens)
    {
        float acc[4][12];
        #pragma unroll
        for (int t = 0; t < 4; ++t)
            #pragma unroll
            for (int j = 0; j < 12; ++j) acc[t][j] = 0.f;
        const float* wq = qkvw + jg * 12;
        #pragma unroll 2
        for (int k0 = 0; k0 < 64; k0 += 4) {
            float4 a4[4];
            #pragma unroll
            for (int t = 0; t < 4; ++t)
                a4[t] = *reinterpret_cast<const float4*>(&hn[tg * 4 + t][k0]);
            float4 wv[4][3];
            #pragma unroll
            for (int kk = 0; kk < 4; ++kk)
                #pragma unroll
                for (int c = 0; c < 3; ++c)
                    wv[kk][c] = *reinterpret_cast<const float4*>(wq + (k0 + kk) * 192 + c * 4);
            #pragma unroll
            for (int kk = 0; kk < 4; ++kk)
                #pragma unroll
                for (int t = 0; t < 4; ++t) {
                    float a = kk == 0 ? a4[t].x : kk == 1 ? a4[t].y : kk == 2 ? a4[t].z : a4[t].w;
                    #pragma unroll
                    for (int c = 0; c < 3; ++c) {
                        acc[t][c * 4 + 0] = fmaf(a, wv[kk][c].x, acc[t][c * 4 + 0]);
                        acc[t][c * 4 + 1] = fmaf(a, wv[kk][c].y, acc[t][c * 4 + 1]);
                        acc[t][c * 4 + 2] = fmaf(a, wv[kk][c].z, acc[t][c * 4 + 2]);
                        acc[t][c * 4 + 3] = fmaf(a, wv[kk][c].w, acc[t][c * 4 + 3]);
                    }
                }
        }
        #pragma unroll
        for (int t = 0; t < 4; ++t)
            #pragma unroll
            for (int c = 0; c < 3; ++c)
                *reinterpret_cast<float4*>(&qs[tg * 4 + t][jg * 12 + c * 4]) =
                    make_float4(acc[t][c * 4], acc[t][c * 4 + 1], acc[t][c * 4 + 2], acc[t][c * 4 + 3]);
    }
    __syncthreads();

    // ---- C: attention. thread = (head hh, row n, d-half dh); all 256 lanes.
    {
        int hh = tid >> 7, n = (tid >> 1) & 63, dh = tid & 1;
        int qo = hh * 32 + dh * 16;
        float q[16];
        #pragma unroll
        for (int c = 0; c < 4; ++c) {
            float4 t4 = *reinterpret_cast<const float4*>(&qs[n][qo + c * 4]);
            q[c * 4] = t4.x; q[c * 4 + 1] = t4.y; q[c * 4 + 2] = t4.z; q[c * 4 + 3] = t4.w;
        }
        float s[64];
        int myrid = SHIFTED ? rid_s[n] : 0;
        const float scale = 0.17677669529663687f;
        #pragma unroll
        for (int m = 0; m < 64; ++m) {
            float a = 0.f;
            #pragma unroll
            for (int c = 0; c < 4; ++c) {
                float4 kv = *reinterpret_cast<const float4*>(&qs[m][64 + qo + c * 4]);
                a = fmaf(q[c * 4 + 0], kv.x, a);
                a = fmaf(q[c * 4 + 1], kv.y, a);
                a = fmaf(q[c * 4 + 2], kv.z, a);
                a = fmaf(q[c * 4 + 3], kv.w, a);
            }
            a += __shfl_xor(a, 1);     // combine the two d-halves
            a *= scale;
            if (SHIFTED && rid_s[m] != myrid) a -= 100.f;
            s[m] = a;
        }
        float mx = s[0];
        #pragma unroll
        for (int m = 1; m < 64; ++m) mx = fmaxf(mx, s[m]);
        float sum = 0.f;
        #pragma unroll
        for (int m = 0; m < 64; ++m) { float e = __expf(s[m] - mx); s[m] = e; sum += e; }
        float inv = 1.0f / sum;
        float o[16];
        #pragma unroll
        for (int j = 0; j < 16; ++j) o[j] = 0.f;
        #pragma unroll
        for (int m = 0; m < 64; ++m) {
            float p = s[m];
            #pragma unroll
            for (int c = 0; c < 4; ++c) {
                float4 vv = *reinterpret_cast<const float4*>(&qs[m][128 + qo + c * 4]);
                o[c * 4 + 0] = fmaf(p, vv.x, o[c * 4 + 0]);
                o[c * 4 + 1] = fmaf(p, vv.y, o[c * 4 + 1]);
                o[c * 4 + 2] = fmaf(p, vv.z, o[c * 4 + 2]);
                o[c * 4 + 3] = fmaf(p, vv.w, o[c * 4 + 3]);
            }
        }
        #pragma unroll
        for (int c = 0; c < 4; ++c)
            *reinterpret_cast<float4*>(&hn[n][qo + c * 4]) =
                make_float4(o[c * 4] * inv, o[c * 4 + 1] * inv, o[c * 4 + 2] * inv, o[c * 4 + 3] * inv);
    }
    __syncthreads();

    // ---- D: proj GEMM + bias. thread = (jg: 4 ch, tg: 4 tok). out -> qs[..][0:64)
    {
        float acc[4][4];
        #pragma unroll
        for (int t = 0; t < 4; ++t)
            #pragma unroll
            for (int j = 0; j < 4; ++j) acc[t][j] = 0.f;
        const float* wp = projw + jg * 4;
        #pragma unroll 2
        for (int k0 = 0; k0 < 64; k0 += 4) {
            float4 a4[4];
            #pragma unroll
            for (int t = 0; t < 4; ++t)
                a4[t] = *reinterpret_cast<const float4*>(&hn[tg * 4 + t][k0]);
            float4 wv[4];
            #pragma unroll
            for (int kk = 0; kk < 4; ++kk)
                wv[kk] = *reinterpret_cast<const float4*>(wp + (k0 + kk) * 64);
            #pragma unroll
            for (int kk = 0; kk < 4; ++kk)
                #pragma unroll
                for (int t = 0; t < 4; ++t) {
                    float a = kk == 0 ? a4[t].x : kk == 1 ? a4[t].y : kk == 2 ? a4[t].z : a4[t].w;
                    acc[t][0] = fmaf(a, wv[kk].x, acc[t][0]);
                    acc[t][1] = fmaf(a, wv[kk].y, acc[t][1]);
                    acc[t][2] = fmaf(a, wv[kk].z, acc[t][2]);
                    acc[t][3] = fmaf(a, wv[kk].w, acc[t][3]);
                }
        }
        float4 pb4 = *reinterpret_cast<const float4*>(projb + jg * 4);
        #pragma unroll
        for (int t = 0; t < 4; ++t)
            *reinterpret_cast<float4*>(&qs[tg * 4 + t][jg * 4]) =
                make_float4(acc[t][0] + pb4.x, acc[t][1] + pb4.y, acc[t][2] + pb4.z, acc[t][3] + pb4.w);
    }
    __syncthreads();

    // ---- r2 = v + proj-out; RMSNorm(ln2) -> hn (xt)
    {
        #pragma unroll
        for (int c = 0; c < 4; ++c) {
            float4 t4 = *reinterpret_cast<const float4*>(&qs[tok][seg * 16 + c * 4]);
            v[c * 4] += t4.x; v[c * 4 + 1] += t4.y; v[c * 4 + 2] += t4.z; v[c * 4 + 3] += t4.w;
        }
        float ss = 0.f;
        #pragma unroll
        for (int j = 0; j < 16; ++j) ss = fmaf(v[j], v[j], ss);
        ss += __shfl_xor(ss, 1);
        ss += __shfl_xor(ss, 2);
        float r = rsqrtf(ss * (1.0f / 64.0f) + EPSV);
        #pragma unroll
        for (int c = 0; c < 4; ++c) {
            float4 o4;
            o4.x = v[c * 4 + 0] * r * ln2[seg * 16 + c * 4 + 0];
            o4.y = v[c * 4 + 1] * r * ln2[seg * 16 + c * 4 + 1];
            o4.z = v[c * 4 + 2] * r * ln2[seg * 16 + c * 4 + 2];
            o4.w = v[c * 4 + 3] * r * ln2[seg * 16 + c * 4 + 3];
            *reinterpret_cast<float4*>(&hn[tok][seg * 16 + c * 4]) = o4;
        }
    }
    __syncthreads();

    // ---- MLP1 + GELU. thread = (jg: 8 hid-ch, tg: 4 tok). out -> qs[..][0:128)
    {
        float acc[4][8];
        #pragma unroll
        for (int t = 0; t < 4; ++t)
            #pragma unroll
            for (int j = 0; j < 8; ++j) acc[t][j] = 0.f;
        const float* ww = w1 + jg * 8;
        #pragma unroll 2
        for (int k0 = 0; k0 < 64; k0 += 4) {
            float4 a4[4];
            #pragma unroll
            for (int t = 0; t < 4; ++t)
                a4[t] = *reinterpret_cast<const float4*>(&hn[tg * 4 + t][k0]);
            float4 wv[4][2];
            #pragma unroll
            for (int kk = 0; kk < 4; ++kk)
                #pragma unroll
                for (int c = 0; c < 2; ++c)
                    wv[kk][c] = *reinterpret_cast<const float4*>(ww + (k0 + kk) * 128 + c * 4);
            #pragma unroll
            for (int kk = 0; kk < 4; ++kk)
                #pragma unroll
                for (int t = 0; t < 4; ++t) {
                    float a = kk == 0 ? a4[t].x : kk == 1 ? a4[t].y : kk == 2 ? a4[t].z : a4[t].w;
                    #pragma unroll
                    for (int c = 0; c < 2; ++c) {
                        acc[t][c * 4 + 0] = fmaf(a, wv[kk][c].x, acc[t][c * 4 + 0]);
                        acc[t][c * 4 + 1] = fmaf(a, wv[kk][c].y, acc[t][c * 4 + 1]);
                        acc[t][c * 4 + 2] = fmaf(a, wv[kk][c].z, acc[t][c * 4 + 2]);
                        acc[t][c * 4 + 3] = fmaf(a, wv[kk][c].w, acc[t][c * 4 + 3]);
                    }
                }
        }
        #pragma unroll
        for (int t = 0; t < 4; ++t) {
            float g[8];
            #pragma unroll
            for (int j = 0; j < 8; ++j) {
                float u = acc[t][j] + b1[jg * 8 + j];
                g[j] = 0.5f * u * (1.0f + erff(u * 0.70710678118654752f));
            }
            *reinterpret_cast<float4*>(&qs[tg * 4 + t][jg * 8 + 0]) = make_float4(g[0], g[1], g[2], g[3]);
            *reinterpret_cast<float4*>(&qs[tg * 4 + t][jg * 8 + 4]) = make_float4(g[4], g[5], g[6], g[7]);
        }
    }
    __syncthreads();

    // ---- MLP2 + bias. thread = (jg: 4 ch, tg: 4 tok). out -> hn[..][0:64)
    {
        float acc[4][4];
        #pragma unroll
        for (int t = 0; t < 4; ++t)
            #pragma unroll
            for (int j = 0; j < 4; ++j) acc[t][j] = 0.f;
        const float* ww = w2 + jg * 4;
        #pragma unroll 2
        for (int k0 = 0; k0 < 128; k0 += 4) {
            float4 a4[4];
            #pragma unroll
            for (int t = 0; t < 4; ++t)
                a4[t] = *reinterpret_cast<const float4*>(&qs[tg * 4 + t][k0]);
            float4 wv[4];
            #pragma unroll
            for (int kk = 0; kk < 4; ++kk)
                wv[kk] = *reinterpret_cast<const float4*>(ww + (k0 + kk) * 64);
            #pragma unroll
            for (int kk = 0; kk < 4; ++kk)
                #pragma unroll
                for (int t = 0; t < 4; ++t) {
                    float a = kk == 0 ? a4[t].x : kk == 1 ? a4[t].y : kk == 2 ? a4[t].z : a4[t].w;
                    acc[t][0] = fmaf(a, wv[kk].x, acc[t][0]);
                    acc[t][1] = fmaf(a, wv[kk].y, acc[t][1]);
                    acc[t][2] = fmaf(a, wv[kk].z, acc[t][2]);
                    acc[t][3] = fmaf(a, wv[kk].w, acc[t][3]);
                }
        }
        float4 bb = *reinterpret_cast<const float4*>(b2 + jg * 4);
        #pragma unroll
        for (int t = 0; t < 4; ++t)
            *reinterpret_cast<float4*>(&hn[tg * 4 + t][jg * 4]) =
                make_float4(acc[t][0] + bb.x, acc[t][1] + bb.y, acc[t][2] + bb.z, acc[t][3] + bb.w);
    }
    __syncthreads();

    // ---- final: h[lidx] = r2 + mlp-out  (single global write of the layer)
    {
        float* op = h + (size_t)lidx * 64 + seg * 16;
        #pragma unroll
        for (int c = 0; c < 4; ++c) {
            float4 t4 = *reinterpret_cast<const float4*>(&hn[tok][seg * 16 + c * 4]);
            *reinterpret_cast<float4*>(op + c * 4) =
                make_float4(v[c * 4] + t4.x, v[c * 4 + 1] + t4.y, v[c * 4 + 2] + t4.z, v[c * 4 + 3] + t4.w);
        }
    }
}

// --------------------------------------------------------------- down + fold
__global__ __launch_bounds__(256) void k_down(const float* __restrict__ h,
        const float* __restrict__ wp, const float* __restrict__ bp,
        const float* __restrict__ wc, const float* __restrict__ bc,
        float* __restrict__ out) {
    int t = blockIdx.x * 256 + threadIdx.x;   // L*2 threads
    int tok = t >> 1, pc = t & 1;
    const float* wsel = pc ? wc : wp;
    const float* bsel = pc ? bc : bp;
    float* obase = out + (size_t)pc * (64u * 256u * 256u);
    float hv[64];
    const float* hp = h + (size_t)tok * 64;
    #pragma unroll
    for (int j4 = 0; j4 < 16; ++j4) {
        float4 t4 = *reinterpret_cast<const float4*>(hp + j4 * 4);
        hv[j4 * 4] = t4.x; hv[j4 * 4 + 1] = t4.y; hv[j4 * 4 + 2] = t4.z; hv[j4 * 4 + 3] = t4.w;
    }
    float acc[32];
    #pragma unroll
    for (int j = 0; j < 32; ++j) acc[j] = bsel[j];
    #pragma unroll 4
    for (int k = 0; k < 64; ++k) {
        float a = hv[k];
        const float* wr = wsel + k * 32;
        #pragma unroll
        for (int j = 0; j < 32; ++j) acc[j] = fmaf(a, wr[j], acc[j]);
    }
    int xg = tok & 63, yg = (tok >> 6) & 63, zg = tok >> 12;
    float* op = obase + ((size_t)(zg * 2) * 256 + yg * 4) * 256 + xg * 4;
    #pragma unroll
    for (int dz = 0; dz < 2; ++dz)
        #pragma unroll
        for (int dy = 0; dy < 4; ++dy) {
            int b = (dz * 4 + dy) * 4;
            *reinterpret_cast<float4*>(op + ((size_t)dz * 256 + dy) * 256) =
                make_float4(acc[b], acc[b + 1], acc[b + 2], acc[b + 3]);
        }
}

// --------------------------------------------------------------------- launch
extern "C" void kernel_launch(void* const* d_in, const int* in_sizes, int n_in,
                              void* d_out, int out_size, void* d_ws, size_t ws_size,
                              hipStream_t stream) {
    const float* x        = (const float*)d_in[0];
    const float* up_w     = (const float*)d_in[1];
    const float* up_b     = (const float*)d_in[2];
    const float* ln1_w    = (const float*)d_in[3];
    const float* qkv_w    = (const float*)d_in[4];
    const float* proj_w   = (const float*)d_in[5];
    const float* proj_b   = (const float*)d_in[6];
    const float* ln2_w    = (const float*)d_in[7];
    const float* mlp_w1   = (const float*)d_in[8];
    const float* mlp_b1   = (const float*)d_in[9];
    const float* mlp_w2   = (const float*)d_in[10];
    const float* mlp_b2   = (const float*)d_in[11];
    const float* down_p_w = (const float*)d_in[12];
    const float* down_p_b = (const float*)d_in[13];
    const float* down_c_w = (const float*)d_in[14];
    const float* down_c_b = (const float*)d_in[15];
    float* out = (float*)d_out;
    float* h   = (float*)d_ws;   // 131072 * 64 floats = 32 MB

    k_embed<<<2048, 256, 0, stream>>>(x, up_w, up_b, h);
    for (int i = 0; i < 16; ++i) {
        const float* a0 = ln1_w + i * 64;
        const float* a1 = qkv_w  + (size_t)i * 64 * 192;
        const float* a2 = proj_w + (size_t)i * 64 * 64;
        const float* a3 = proj_b + i * 64;
        const float* a4 = ln2_w + i * 64;
        const float* a5 = mlp_w1 + (size_t)i * 64 * 128;
        const float* a6 = mlp_b1 + i * 128;
        const float* a7 = mlp_w2 + (size_t)i * 128 * 64;
        const float* a8 = mlp_b2 + i * 64;
        if (i & 1) k_layer<1><<<2048, 256, 0, stream>>>(h, a0, a1, a2, a3, a4, a5, a6, a7, a8);
        else       k_layer<0><<<2048, 256, 0, stream>>>(h, a0, a1, a2, a3, a4, a5, a6, a7, a8);
    }
    k_down<<<1024, 256, 0, stream>>>(h, down_p_w, down_p_b, down_c_w, down_c_b, out);
}

// Round 9
// 1855.689 us; speedup vs baseline: 10.2099x; 1.9140x over previous
//
#include <hip/hip_runtime.h>
#include <hip/hip_bf16.h>

// 3D Swin: grid (32,64,64), L=131072, C=64, WIN=4 (N=64), 2 heads x 32,
// shift=2 odd layers, FFN 128, 16 layers.
// GEMMs on MFMA (split-bf16 hi/lo, 3-product error compensation);
// attention core in VALU fp32.

#define EPSV 1.1920929e-07f
#define QSW 196          // qs row stride (floats)
#define HAW 72           // hA row stride (ushorts)
#define HA_LO (64*72)    // offset of lo plane in hA
#define HTW 136          // ht row stride (ushorts)
#define HT_LO (64*136)

typedef short short8 __attribute__((ext_vector_type(8)));
typedef float f32x4 __attribute__((ext_vector_type(4)));

#define MFMA3(d, ah_, al_, bh_, bl_)                                     \
    d = __builtin_amdgcn_mfma_f32_16x16x32_bf16(ah_, bh_, d, 0, 0, 0);   \
    d = __builtin_amdgcn_mfma_f32_16x16x32_bf16(ah_, bl_, d, 0, 0, 0);   \
    d = __builtin_amdgcn_mfma_f32_16x16x32_bf16(al_, bh_, d, 0, 0, 0);

__device__ __forceinline__ void split2(float v, short& hs, short& ls) {
    unsigned u = __float_as_uint(v);
    float hf = __uint_as_float(u & 0xFFFF0000u);
    float lf = v - hf;                       // exact
    hs = (short)(u >> 16);
    ls = (short)(__float_as_uint(lf) >> 16);
}

// ---------------------------------------------------------------- patch embed
__global__ __launch_bounds__(256) void k_embed(const float* __restrict__ x,
        const float* __restrict__ up_w, const float* __restrict__ up_b,
        float* __restrict__ h) {
    int t = blockIdx.x * 256 + threadIdx.x;       // L*4 threads
    int tok = t >> 2, seg = t & 3;
    int xg = tok & 63, yg = (tok >> 6) & 63, zg = tok >> 12;
    const float* xp = x + ((size_t)(zg * 2) * 256 + yg * 4) * 256 + xg * 4;
    float p[32];
    #pragma unroll
    for (int dz = 0; dz < 2; ++dz)
        #pragma unroll
        for (int dy = 0; dy < 4; ++dy) {
            float4 v = *reinterpret_cast<const float4*>(xp + ((size_t)dz * 256 + dy) * 256);
            int b = (dz * 4 + dy) * 4;
            p[b] = v.x; p[b + 1] = v.y; p[b + 2] = v.z; p[b + 3] = v.w;
        }
    float acc[16];
    #pragma unroll
    for (int j = 0; j < 16; ++j) acc[j] = up_b[seg * 16 + j];
    #pragma unroll
    for (int k = 0; k < 32; ++k) {
        float a = p[k];
        const float* wr = up_w + k * 64 + seg * 16;
        #pragma unroll
        for (int j = 0; j < 16; ++j) acc[j] = fmaf(a, wr[j], acc[j]);
    }
    float* op = h + (size_t)tok * 64 + seg * 16;
    #pragma unroll
    for (int j = 0; j < 16; ++j) op[j] = acc[j];
}

// -------------------------------------------------------- fused full layer
template <int SHIFTED>
__global__ __launch_bounds__(256, 2) void k_layer(float* __restrict__ h,
        const float* __restrict__ ln1, const float* __restrict__ qkvw,
        const float* __restrict__ projw, const float* __restrict__ projb,
        const float* __restrict__ ln2, const float* __restrict__ w1,
        const float* __restrict__ b1, const float* __restrict__ w2,
        const float* __restrict__ b2) {
    // hA: bf16 hi/lo planes of 64x64 activations (norm1 out, attn out, norm2 out);
    //     also reinterpreted as float[64][72] for mlp2 output.
    __shared__ __align__(16) unsigned short hA[2 * 64 * HAW];   // 18432 B
    // qs: fp32 64x196 (q|k|v, proj-out); later overlaid by bf16 hi/lo mlp hidden.
    __shared__ __align__(16) float qs[64 * QSW];                // 50176 B
    __shared__ int rid_s[64];

    float* hAf = (float*)hA;                        // [64][72] floats (same bytes)
    unsigned short* ht_hi = (unsigned short*)qs;    // [64][136]
    unsigned short* ht_lo = (unsigned short*)qs + HT_LO;

    int w = blockIdx.x;
    int wx = w & 15, wy = (w >> 4) & 15, wz = w >> 8;
    int tid = threadIdx.x;
    int tok = tid >> 2, seg = tid & 3;
    int wv = tid >> 6, lane = tid & 63, lr = lane & 15, lg = lane >> 4;

    float v[16];        // residual slice (tok, seg*16..+16); becomes r2
    int lidx;

    // ---- A: gather (shift-roll), RMSNorm(ln1) -> hA (bf16 split)
    {
        int nz = tok >> 4, ny = (tok >> 2) & 3, nx = tok & 3;
        int gz = wz * 4 + nz, gy = wy * 4 + ny, gx = wx * 4 + nx;
        int sz, sy, sx;
        if (SHIFTED) { sz = (gz + 2) & 31; sy = (gy + 2) & 63; sx = (gx + 2) & 63; }
        else         { sz = gz; sy = gy; sx = gx; }
        lidx = (sz * 64 + sy) * 64 + sx;
        if (SHIFTED && seg == 0) {
            int rz = gz >= 30 ? 2 : (gz >= 28 ? 1 : 0);
            int ry = gy >= 62 ? 2 : (gy >= 60 ? 1 : 0);
            int rx = gx >= 62 ? 2 : (gx >= 60 ? 1 : 0);
            rid_s[tok] = rz * 9 + ry * 3 + rx;
        }
        const float* hp = h + (size_t)lidx * 64 + seg * 16;
        #pragma unroll
        for (int c = 0; c < 4; ++c) {
            float4 t4 = *reinterpret_cast<const float4*>(hp + c * 4);
            v[c * 4] = t4.x; v[c * 4 + 1] = t4.y; v[c * 4 + 2] = t4.z; v[c * 4 + 3] = t4.w;
        }
        float ss = 0.f;
        #pragma unroll
        for (int j = 0; j < 16; ++j) ss = fmaf(v[j], v[j], ss);
        ss += __shfl_xor(ss, 1);
        ss += __shfl_xor(ss, 2);
        float r = rsqrtf(ss * (1.0f / 64.0f) + EPSV);
        short8 sh[2], sl[2];
        #pragma unroll
        for (int j = 0; j < 16; ++j) {
            float nv = v[j] * r * ln1[seg * 16 + j];
            short hs, ls; split2(nv, hs, ls);
            sh[j >> 3][j & 7] = hs; sl[j >> 3][j & 7] = ls;
        }
        *reinterpret_cast<short8*>(&hA[tok * HAW + seg * 16])         = sh[0];
        *reinterpret_cast<short8*>(&hA[tok * HAW + seg * 16 + 8])     = sh[1];
        *reinterpret_cast<short8*>(&hA[HA_LO + tok * HAW + seg * 16])     = sl[0];
        *reinterpret_cast<short8*>(&hA[HA_LO + tok * HAW + seg * 16 + 8]) = sl[1];
    }
    __syncthreads();

    // ---- B: qkv = hn @ qkvw  (MFMA; wave wv owns output cols 48wv..48wv+48)
    {
        short8 ah[4][2], al[4][2];
        #pragma unroll
        for (int mt = 0; mt < 4; ++mt)
            #pragma unroll
            for (int ks = 0; ks < 2; ++ks) {
                int off = (mt * 16 + lr) * HAW + ks * 32 + lg * 8;
                ah[mt][ks] = *reinterpret_cast<const short8*>(&hA[off]);
                al[mt][ks] = *reinterpret_cast<const short8*>(&hA[HA_LO + off]);
            }
        #pragma unroll
        for (int nt = 0; nt < 3; ++nt) {
            int c0 = wv * 48 + nt * 16;
            short8 bh[2], bl[2];
            #pragma unroll
            for (int ks = 0; ks < 2; ++ks) {
                const float* p = qkvw + (size_t)(ks * 32 + lg * 8) * 192 + c0 + lr;
                #pragma unroll
                for (int e = 0; e < 8; ++e) {
                    short hs, ls; split2(p[e * 192], hs, ls);
                    bh[ks][e] = hs; bl[ks][e] = ls;
                }
            }
            f32x4 acc[4];
            #pragma unroll
            for (int mt = 0; mt < 4; ++mt) acc[mt] = (f32x4)(0.f);
            #pragma unroll
            for (int mt = 0; mt < 4; ++mt)
                #pragma unroll
                for (int ks = 0; ks < 2; ++ks) {
                    MFMA3(acc[mt], ah[mt][ks], al[mt][ks], bh[ks], bl[ks]);
                }
            #pragma unroll
            for (int mt = 0; mt < 4; ++mt)
                #pragma unroll
                for (int j = 0; j < 4; ++j)
                    qs[(mt * 16 + lg * 4 + j) * QSW + c0 + lr] = acc[mt][j];
        }
    }
    __syncthreads();

    // ---- C: attention (VALU fp32). thread = (head hh, row n, d-half dh).
    {
        int hh = tid >> 7, n = (tid >> 1) & 63, dh = tid & 1;
        int qo = hh * 32 + dh * 16;
        float q[16];
        #pragma unroll
        for (int c = 0; c < 4; ++c) {
            float4 t4 = *reinterpret_cast<const float4*>(&qs[n * QSW + qo + c * 4]);
            q[c * 4] = t4.x; q[c * 4 + 1] = t4.y; q[c * 4 + 2] = t4.z; q[c * 4 + 3] = t4.w;
        }
        float s[64];
        int myrid = SHIFTED ? rid_s[n] : 0;
        const float scale = 0.17677669529663687f;
        #pragma unroll
        for (int m = 0; m < 64; ++m) {
            float a = 0.f;
            #pragma unroll
            for (int c = 0; c < 4; ++c) {
                float4 kv = *reinterpret_cast<const float4*>(&qs[m * QSW + 64 + qo + c * 4]);
                a = fmaf(q[c * 4 + 0], kv.x, a);
                a = fmaf(q[c * 4 + 1], kv.y, a);
                a = fmaf(q[c * 4 + 2], kv.z, a);
                a = fmaf(q[c * 4 + 3], kv.w, a);
            }
            a += __shfl_xor(a, 1);     // combine d-halves
            a *= scale;
            if (SHIFTED && rid_s[m] != myrid) a -= 100.f;
            s[m] = a;
        }
        float mx = s[0];
        #pragma unroll
        for (int m = 1; m < 64; ++m) mx = fmaxf(mx, s[m]);
        float sum = 0.f;
        #pragma unroll
        for (int m = 0; m < 64; ++m) { float e = __expf(s[m] - mx); s[m] = e; sum += e; }
        float inv = 1.0f / sum;
        float o[16];
        #pragma unroll
        for (int j = 0; j < 16; ++j) o[j] = 0.f;
        #pragma unroll
        for (int m = 0; m < 64; ++m) {
            float p = s[m];
            #pragma unroll
            for (int c = 0; c < 4; ++c) {
                float4 vv = *reinterpret_cast<const float4*>(&qs[m * QSW + 128 + qo + c * 4]);
                o[c * 4 + 0] = fmaf(p, vv.x, o[c * 4 + 0]);
                o[c * 4 + 1] = fmaf(p, vv.y, o[c * 4 + 1]);
                o[c * 4 + 2] = fmaf(p, vv.z, o[c * 4 + 2]);
                o[c * 4 + 3] = fmaf(p, vv.w, o[c * 4 + 3]);
            }
        }
        short8 sh[2], sl[2];
        #pragma unroll
        for (int j = 0; j < 16; ++j) {
            short hs, ls; split2(o[j] * inv, hs, ls);
            sh[j >> 3][j & 7] = hs; sl[j >> 3][j & 7] = ls;
        }
        *reinterpret_cast<short8*>(&hA[n * HAW + qo])             = sh[0];
        *reinterpret_cast<short8*>(&hA[n * HAW + qo + 8])         = sh[1];
        *reinterpret_cast<short8*>(&hA[HA_LO + n * HAW + qo])     = sl[0];
        *reinterpret_cast<short8*>(&hA[HA_LO + n * HAW + qo + 8]) = sl[1];
    }
    __syncthreads();

    // ---- D: proj (MFMA) + bias -> qs[.., 0:64)
    {
        short8 ah[4][2], al[4][2];
        #pragma unroll
        for (int mt = 0; mt < 4; ++mt)
            #pragma unroll
            for (int ks = 0; ks < 2; ++ks) {
                int off = (mt * 16 + lr) * HAW + ks * 32 + lg * 8;
                ah[mt][ks] = *reinterpret_cast<const short8*>(&hA[off]);
                al[mt][ks] = *reinterpret_cast<const short8*>(&hA[HA_LO + off]);
            }
        int c0 = wv * 16;
        short8 bh[2], bl[2];
        #pragma unroll
        for (int ks = 0; ks < 2; ++ks) {
            const float* p = projw + (size_t)(ks * 32 + lg * 8) * 64 + c0 + lr;
            #pragma unroll
            for (int e = 0; e < 8; ++e) {
                short hs, ls; split2(p[e * 64], hs, ls);
                bh[ks][e] = hs; bl[ks][e] = ls;
            }
        }
        f32x4 acc[4];
        #pragma unroll
        for (int mt = 0; mt < 4; ++mt) acc[mt] = (f32x4)(0.f);
        #pragma unroll
        for (int mt = 0; mt < 4; ++mt)
            #pragma unroll
            for (int ks = 0; ks < 2; ++ks) {
                MFMA3(acc[mt], ah[mt][ks], al[mt][ks], bh[ks], bl[ks]);
            }
        float pb = projb[c0 + lr];
        #pragma unroll
        for (int mt = 0; mt < 4; ++mt)
            #pragma unroll
            for (int j = 0; j < 4; ++j)
                qs[(mt * 16 + lg * 4 + j) * QSW + c0 + lr] = acc[mt][j] + pb;
    }
    __syncthreads();

    // ---- E: r2 = v + proj-out; RMSNorm(ln2) -> hA (bf16 split)
    {
        #pragma unroll
        for (int j = 0; j < 16; ++j) v[j] += qs[tok * QSW + seg * 16 + j];
        float ss = 0.f;
        #pragma unroll
        for (int j = 0; j < 16; ++j) ss = fmaf(v[j], v[j], ss);
        ss += __shfl_xor(ss, 1);
        ss += __shfl_xor(ss, 2);
        float r = rsqrtf(ss * (1.0f / 64.0f) + EPSV);
        short8 sh[2], sl[2];
        #pragma unroll
        for (int j = 0; j < 16; ++j) {
            float nv = v[j] * r * ln2[seg * 16 + j];
            short hs, ls; split2(nv, hs, ls);
            sh[j >> 3][j & 7] = hs; sl[j >> 3][j & 7] = ls;
        }
        *reinterpret_cast<short8*>(&hA[tok * HAW + seg * 16])         = sh[0];
        *reinterpret_cast<short8*>(&hA[tok * HAW + seg * 16 + 8])     = sh[1];
        *reinterpret_cast<short8*>(&hA[HA_LO + tok * HAW + seg * 16])     = sl[0];
        *reinterpret_cast<short8*>(&hA[HA_LO + tok * HAW + seg * 16 + 8]) = sl[1];
    }
    __syncthreads();

    // ---- F: mlp1 (MFMA) + bias + GELU -> ht (bf16 split, overlaying qs)
    {
        short8 ah[4][2], al[4][2];
        #pragma unroll
        for (int mt = 0; mt < 4; ++mt)
            #pragma unroll
            for (int ks = 0; ks < 2; ++ks) {
                int off = (mt * 16 + lr) * HAW + ks * 32 + lg * 8;
                ah[mt][ks] = *reinterpret_cast<const short8*>(&hA[off]);
                al[mt][ks] = *reinterpret_cast<const short8*>(&hA[HA_LO + off]);
            }
        // NOTE: ht overlays qs; proj-out (qs cols 0:64) was consumed in phase E,
        // and the barrier above orders E-reads before these writes.
        #pragma unroll
        for (int nt = 0; nt < 2; ++nt) {
            int c0 = wv * 32 + nt * 16;
            short8 bh[2], bl[2];
            #pragma unroll
            for (int ks = 0; ks < 2; ++ks) {
                const float* p = w1 + (size_t)(ks * 32 + lg * 8) * 128 + c0 + lr;
                #pragma unroll
                for (int e = 0; e < 8; ++e) {
                    short hs, ls; split2(p[e * 128], hs, ls);
                    bh[ks][e] = hs; bl[ks][e] = ls;
                }
            }
            f32x4 acc[4];
            #pragma unroll
            for (int mt = 0; mt < 4; ++mt) acc[mt] = (f32x4)(0.f);
            #pragma unroll
            for (int mt = 0; mt < 4; ++mt)
                #pragma unroll
                for (int ks = 0; ks < 2; ++ks) {
                    MFMA3(acc[mt], ah[mt][ks], al[mt][ks], bh[ks], bl[ks]);
                }
            float bb = b1[c0 + lr];
            #pragma unroll
            for (int mt = 0; mt < 4; ++mt)
                #pragma unroll
                for (int j = 0; j < 4; ++j) {
                    float u = acc[mt][j] + bb;
                    float g = 0.5f * u * (1.0f + erff(u * 0.70710678118654752f));
                    short hs, ls; split2(g, hs, ls);
                    int off = (mt * 16 + lg * 4 + j) * HTW + c0 + lr;
                    ht_hi[off] = (unsigned short)hs;
                    ht_lo[off] = (unsigned short)ls;
                }
        }
    }
    __syncthreads();

    // ---- G: mlp2 (MFMA, K=128) + bias -> hAf (fp32, overlaying hA)
    {
        int c0 = wv * 16;
        f32x4 acc[4];
        #pragma unroll
        for (int mt = 0; mt < 4; ++mt) acc[mt] = (f32x4)(0.f);
        #pragma unroll
        for (int ks = 0; ks < 4; ++ks) {
            short8 bh, bl;
            const float* p = w2 + (size_t)(ks * 32 + lg * 8) * 64 + c0 + lr;
            #pragma unroll
            for (int e = 0; e < 8; ++e) {
                short hs, ls; split2(p[e * 64], hs, ls);
                bh[e] = hs; bl[e] = ls;
            }
            #pragma unroll
            for (int mt = 0; mt < 4; ++mt) {
                int off = (mt * 16 + lr) * HTW + ks * 32 + lg * 8;
                short8 ah = *reinterpret_cast<const short8*>(&ht_hi[off]);
                short8 al = *reinterpret_cast<const short8*>(&ht_lo[off]);
                MFMA3(acc[mt], ah, al, bh, bl);
            }
        }
        __syncthreads();   // hA (xt) fully consumed in phase F; safe to overwrite as fp32
        float bb = b2[c0 + lr];
        #pragma unroll
        for (int mt = 0; mt < 4; ++mt)
            #pragma unroll
            for (int j = 0; j < 4; ++j)
                hAf[(mt * 16 + lg * 4 + j) * HAW + c0 + lr] = acc[mt][j] + bb;
    }
    __syncthreads();

    // ---- H: h[lidx] = r2 + mlp-out
    {
        float* op = h + (size_t)lidx * 64 + seg * 16;
        #pragma unroll
        for (int c = 0; c < 4; ++c) {
            float4 o4;
            o4.x = v[c * 4 + 0] + hAf[tok * HAW + seg * 16 + c * 4 + 0];
            o4.y = v[c * 4 + 1] + hAf[tok * HAW + seg * 16 + c * 4 + 1];
            o4.z = v[c * 4 + 2] + hAf[tok * HAW + seg * 16 + c * 4 + 2];
            o4.w = v[c * 4 + 3] + hAf[tok * HAW + seg * 16 + c * 4 + 3];
            *reinterpret_cast<float4*>(op + c * 4) = o4;
        }
    }
}

// --------------------------------------------------------------- down + fold
__global__ __launch_bounds__(256) void k_down(const float* __restrict__ h,
        const float* __restrict__ wp, const float* __restrict__ bp,
        const float* __restrict__ wc, const float* __restrict__ bc,
        float* __restrict__ out) {
    int t = blockIdx.x * 256 + threadIdx.x;   // L*2 threads
    int tok = t >> 1, pc = t & 1;
    const float* wsel = pc ? wc : wp;
    const float* bsel = pc ? bc : bp;
    float* obase = out + (size_t)pc * (64u * 256u * 256u);
    float hv[64];
    const float* hp = h + (size_t)tok * 64;
    #pragma unroll
    for (int j4 = 0; j4 < 16; ++j4) {
        float4 t4 = *reinterpret_cast<const float4*>(hp + j4 * 4);
        hv[j4 * 4] = t4.x; hv[j4 * 4 + 1] = t4.y; hv[j4 * 4 + 2] = t4.z; hv[j4 * 4 + 3] = t4.w;
    }
    float acc[32];
    #pragma unroll
    for (int j = 0; j < 32; ++j) acc[j] = bsel[j];
    #pragma unroll 4
    for (int k = 0; k < 64; ++k) {
        float a = hv[k];
        const float* wr = wsel + k * 32;
        #pragma unroll
        for (int j = 0; j < 32; ++j) acc[j] = fmaf(a, wr[j], acc[j]);
    }
    int xg = tok & 63, yg = (tok >> 6) & 63, zg = tok >> 12;
    float* op = obase + ((size_t)(zg * 2) * 256 + yg * 4) * 256 + xg * 4;
    #pragma unroll
    for (int dz = 0; dz < 2; ++dz)
        #pragma unroll
        for (int dy = 0; dy < 4; ++dy) {
            int b = (dz * 4 + dy) * 4;
            *reinterpret_cast<float4*>(op + ((size_t)dz * 256 + dy) * 256) =
                make_float4(acc[b], acc[b + 1], acc[b + 2], acc[b + 3]);
        }
}

// --------------------------------------------------------------------- launch
extern "C" void kernel_launch(void* const* d_in, const int* in_sizes, int n_in,
                              void* d_out, int out_size, void* d_ws, size_t ws_size,
                              hipStream_t stream) {
    const float* x        = (const float*)d_in[0];
    const float* up_w     = (const float*)d_in[1];
    const float* up_b     = (const float*)d_in[2];
    const float* ln1_w    = (const float*)d_in[3];
    const float* qkv_w    = (const float*)d_in[4];
    const float* proj_w   = (const float*)d_in[5];
    const float* proj_b   = (const float*)d_in[6];
    const float* ln2_w    = (const float*)d_in[7];
    const float* mlp_w1   = (const float*)d_in[8];
    const float* mlp_b1   = (const float*)d_in[9];
    const float* mlp_w2   = (const float*)d_in[10];
    const float* mlp_b2   = (const float*)d_in[11];
    const float* down_p_w = (const float*)d_in[12];
    const float* down_p_b = (const float*)d_in[13];
    const float* down_c_w = (const float*)d_in[14];
    const float* down_c_b = (const float*)d_in[15];
    float* out = (float*)d_out;
    float* h   = (float*)d_ws;   // 131072 * 64 floats = 32 MB

    k_embed<<<2048, 256, 0, stream>>>(x, up_w, up_b, h);
    for (int i = 0; i < 16; ++i) {
        const float* a0 = ln1_w + i * 64;
        const float* a1 = qkv_w  + (size_t)i * 64 * 192;
        const float* a2 = proj_w + (size_t)i * 64 * 64;
        const float* a3 = proj_b + i * 64;
        const float* a4 = ln2_w + i * 64;
        const float* a5 = mlp_w1 + (size_t)i * 64 * 128;
        const float* a6 = mlp_b1 + i * 128;
        const float* a7 = mlp_w2 + (size_t)i * 128 * 64;
        const float* a8 = mlp_b2 + i * 64;
        if (i & 1) k_layer<1><<<2048, 256, 0, stream>>>(h, a0, a1, a2, a3, a4, a5, a6, a7, a8);
        else       k_layer<0><<<2048, 256, 0, stream>>>(h, a0, a1, a2, a3, a4, a5, a6, a7, a8);
    }
    k_down<<<1024, 256, 0, stream>>>(h, down_p_w, down_p_b, down_c_w, down_c_b, out);
}

// Round 10
// 1696.620 us; speedup vs baseline: 11.1671x; 1.0938x over previous
//
#include <hip/hip_runtime.h>
#include <hip/hip_bf16.h>

// 3D Swin: grid (32,64,64), L=131072, C=64, WIN=4 (N=64), 2 heads x 32,
// shift=2 odd layers, FFN 128, 16 layers.
// GEMMs on MFMA (split-bf16 hi/lo, 3-product error compensation), with
// weights pre-split ONCE into a fragment-major bf16 table in d_ws.
// Attention core in VALU fp32.

#define EPSV 1.1920929e-07f
#define QSW 196          // qs row stride (floats)
#define HAW 72           // hA row stride (ushorts)
#define HA_LO (64*72)    // offset of lo plane in hA
#define HTW 136          // ht row stride (ushorts)
#define HT_LO (64*136)

// pre-split weight table (ushorts): per layer 32768 = qkv 12288 | proj 4096 | w1 8192 | w2 8192
#define LAYER_WSZ 32768
#define WOFF_QKV  0
#define WOFF_PROJ 12288
#define WOFF_W1   16384
#define WOFF_W2   24576
#define WTOT      (16 * LAYER_WSZ)      // 524288 per plane

typedef short short8 __attribute__((ext_vector_type(8)));
typedef float f32x4 __attribute__((ext_vector_type(4)));

#define MFMA3(d, ah_, al_, bh_, bl_)                                     \
    d = __builtin_amdgcn_mfma_f32_16x16x32_bf16(ah_, bh_, d, 0, 0, 0);   \
    d = __builtin_amdgcn_mfma_f32_16x16x32_bf16(ah_, bl_, d, 0, 0, 0);   \
    d = __builtin_amdgcn_mfma_f32_16x16x32_bf16(al_, bh_, d, 0, 0, 0);

__device__ __forceinline__ void split2(float v, short& hs, short& ls) {
    unsigned u = __float_as_uint(v);
    float hf = __uint_as_float(u & 0xFFFF0000u);
    float lf = v - hf;                       // exact
    hs = (short)(u >> 16);
    ls = (short)(__float_as_uint(lf) >> 16);
}

// ------------------------------------------- weight pre-split (runs once/launch)
// Fragment-major layout: idx = ((ct*nks+ks)*4+lg)*128 + lr*8 + e
//   maps to source element (k = ks*32+lg*8+e, c = ct*16+lr).
__global__ __launch_bounds__(256) void k_wsplit(const float* __restrict__ qkv_w,
        const float* __restrict__ proj_w, const float* __restrict__ w1,
        const float* __restrict__ w2, unsigned short* __restrict__ wsout) {
    int t = blockIdx.x * 256 + threadIdx.x;     // WTOT threads
    int layer = t >> 15;
    int r = t & 32767;
    const float* src; int ncols, idx, nks;
    if (r < WOFF_PROJ)      { src = qkv_w  + (size_t)layer * 12288; ncols = 192; idx = r;             nks = 2; }
    else if (r < WOFF_W1)   { src = proj_w + (size_t)layer * 4096;  ncols = 64;  idx = r - WOFF_PROJ; nks = 2; }
    else if (r < WOFF_W2)   { src = w1     + (size_t)layer * 8192;  ncols = 128; idx = r - WOFF_W1;   nks = 2; }
    else                    { src = w2     + (size_t)layer * 8192;  ncols = 64;  idx = r - WOFF_W2;   nks = 4; }
    int e  = idx & 7;
    int lr = (idx >> 3) & 15;
    int lg = (idx >> 7) & 3;
    int q  = idx >> 9;               // ct*nks + ks
    int ks = q & (nks - 1);
    int ct = q / nks;
    int k = ks * 32 + lg * 8 + e;
    int c = ct * 16 + lr;
    short hs, ls; split2(src[k * ncols + c], hs, ls);
    wsout[t]        = (unsigned short)hs;
    wsout[WTOT + t] = (unsigned short)ls;
}

// ---------------------------------------------------------------- patch embed
__global__ __launch_bounds__(256) void k_embed(const float* __restrict__ x,
        const float* __restrict__ up_w, const float* __restrict__ up_b,
        float* __restrict__ h) {
    int t = blockIdx.x * 256 + threadIdx.x;       // L*4 threads
    int tok = t >> 2, seg = t & 3;
    int xg = tok & 63, yg = (tok >> 6) & 63, zg = tok >> 12;
    const float* xp = x + ((size_t)(zg * 2) * 256 + yg * 4) * 256 + xg * 4;
    float p[32];
    #pragma unroll
    for (int dz = 0; dz < 2; ++dz)
        #pragma unroll
        for (int dy = 0; dy < 4; ++dy) {
            float4 v = *reinterpret_cast<const float4*>(xp + ((size_t)dz * 256 + dy) * 256);
            int b = (dz * 4 + dy) * 4;
            p[b] = v.x; p[b + 1] = v.y; p[b + 2] = v.z; p[b + 3] = v.w;
        }
    float acc[16];
    #pragma unroll
    for (int j = 0; j < 16; ++j) acc[j] = up_b[seg * 16 + j];
    #pragma unroll
    for (int k = 0; k < 32; ++k) {
        float a = p[k];
        const float* wr = up_w + k * 64 + seg * 16;
        #pragma unroll
        for (int j = 0; j < 16; ++j) acc[j] = fmaf(a, wr[j], acc[j]);
    }
    float* op = h + (size_t)tok * 64 + seg * 16;
    #pragma unroll
    for (int j = 0; j < 16; ++j) op[j] = acc[j];
}

// -------------------------------------------------------- fused full layer
template <int SHIFTED>
__global__ __launch_bounds__(256, 2) void k_layer(float* __restrict__ h,
        const float* __restrict__ ln1,
        const unsigned short* __restrict__ whi, const unsigned short* __restrict__ wlo,
        const float* __restrict__ projb, const float* __restrict__ ln2,
        const float* __restrict__ b1, const float* __restrict__ b2) {
    __shared__ __align__(16) unsigned short hA[2 * 64 * HAW];   // 18432 B
    __shared__ __align__(16) float qs[64 * QSW];                // 50176 B
    __shared__ int rid_s[64];

    float* hAf = (float*)hA;                        // [64][72] floats (same bytes)
    unsigned short* ht_hi = (unsigned short*)qs;    // [64][136]
    unsigned short* ht_lo = (unsigned short*)qs + HT_LO;

    int w = blockIdx.x;
    int wx = w & 15, wy = (w >> 4) & 15, wz = w >> 8;
    int tid = threadIdx.x;
    int tok = tid >> 2, seg = tid & 3;
    int wv = tid >> 6, lane = tid & 63, lr = lane & 15, lg = lane >> 4;

    float v[16];        // residual slice (tok, seg*16..+16); becomes r2
    int lidx;

    // ---- A: gather (shift-roll), RMSNorm(ln1) -> hA (bf16 split)
    {
        int nz = tok >> 4, ny = (tok >> 2) & 3, nx = tok & 3;
        int gz = wz * 4 + nz, gy = wy * 4 + ny, gx = wx * 4 + nx;
        int sz, sy, sx;
        if (SHIFTED) { sz = (gz + 2) & 31; sy = (gy + 2) & 63; sx = (gx + 2) & 63; }
        else         { sz = gz; sy = gy; sx = gx; }
        lidx = (sz * 64 + sy) * 64 + sx;
        if (SHIFTED && seg == 0) {
            int rz = gz >= 30 ? 2 : (gz >= 28 ? 1 : 0);
            int ry = gy >= 62 ? 2 : (gy >= 60 ? 1 : 0);
            int rx = gx >= 62 ? 2 : (gx >= 60 ? 1 : 0);
            rid_s[tok] = rz * 9 + ry * 3 + rx;
        }
        const float* hp = h + (size_t)lidx * 64 + seg * 16;
        #pragma unroll
        for (int c = 0; c < 4; ++c) {
            float4 t4 = *reinterpret_cast<const float4*>(hp + c * 4);
            v[c * 4] = t4.x; v[c * 4 + 1] = t4.y; v[c * 4 + 2] = t4.z; v[c * 4 + 3] = t4.w;
        }
        float ss = 0.f;
        #pragma unroll
        for (int j = 0; j < 16; ++j) ss = fmaf(v[j], v[j], ss);
        ss += __shfl_xor(ss, 1);
        ss += __shfl_xor(ss, 2);
        float r = rsqrtf(ss * (1.0f / 64.0f) + EPSV);
        short8 sh[2], sl[2];
        #pragma unroll
        for (int j = 0; j < 16; ++j) {
            float nv = v[j] * r * ln1[seg * 16 + j];
            short hs, ls; split2(nv, hs, ls);
            sh[j >> 3][j & 7] = hs; sl[j >> 3][j & 7] = ls;
        }
        *reinterpret_cast<short8*>(&hA[tok * HAW + seg * 16])         = sh[0];
        *reinterpret_cast<short8*>(&hA[tok * HAW + seg * 16 + 8])     = sh[1];
        *reinterpret_cast<short8*>(&hA[HA_LO + tok * HAW + seg * 16])     = sl[0];
        *reinterpret_cast<short8*>(&hA[HA_LO + tok * HAW + seg * 16 + 8]) = sl[1];
    }
    __syncthreads();

    // ---- B: qkv = hn @ qkvw  (MFMA; wave wv owns output cols 48wv..48wv+48)
    {
        short8 ah[4][2], al[4][2];
        #pragma unroll
        for (int mt = 0; mt < 4; ++mt)
            #pragma unroll
            for (int ks = 0; ks < 2; ++ks) {
                int off = (mt * 16 + lr) * HAW + ks * 32 + lg * 8;
                ah[mt][ks] = *reinterpret_cast<const short8*>(&hA[off]);
                al[mt][ks] = *reinterpret_cast<const short8*>(&hA[HA_LO + off]);
            }
        #pragma unroll
        for (int nt = 0; nt < 3; ++nt) {
            int ct = wv * 3 + nt;
            int c0 = ct * 16;
            short8 bh[2], bl[2];
            #pragma unroll
            for (int ks = 0; ks < 2; ++ks) {
                int fo = WOFF_QKV + ((ct * 2 + ks) * 4 + lg) * 128 + lr * 8;
                bh[ks] = *reinterpret_cast<const short8*>(&whi[fo]);
                bl[ks] = *reinterpret_cast<const short8*>(&wlo[fo]);
            }
            f32x4 acc[4];
            #pragma unroll
            for (int mt = 0; mt < 4; ++mt) acc[mt] = (f32x4)(0.f);
            #pragma unroll
            for (int mt = 0; mt < 4; ++mt)
                #pragma unroll
                for (int ks = 0; ks < 2; ++ks) {
                    MFMA3(acc[mt], ah[mt][ks], al[mt][ks], bh[ks], bl[ks]);
                }
            #pragma unroll
            for (int mt = 0; mt < 4; ++mt)
                #pragma unroll
                for (int j = 0; j < 4; ++j)
                    qs[(mt * 16 + lg * 4 + j) * QSW + c0 + lr] = acc[mt][j];
        }
    }
    __syncthreads();

    // ---- C: attention (VALU fp32). thread = (head hh, row n, d-half dh).
    {
        int hh = tid >> 7, n = (tid >> 1) & 63, dh = tid & 1;
        int qo = hh * 32 + dh * 16;
        float q[16];
        #pragma unroll
        for (int c = 0; c < 4; ++c) {
            float4 t4 = *reinterpret_cast<const float4*>(&qs[n * QSW + qo + c * 4]);
            q[c * 4] = t4.x; q[c * 4 + 1] = t4.y; q[c * 4 + 2] = t4.z; q[c * 4 + 3] = t4.w;
        }
        float s[64];
        int myrid = SHIFTED ? rid_s[n] : 0;
        const float scale = 0.17677669529663687f;
        #pragma unroll
        for (int m = 0; m < 64; ++m) {
            float a = 0.f;
            #pragma unroll
            for (int c = 0; c < 4; ++c) {
                float4 kv = *reinterpret_cast<const float4*>(&qs[m * QSW + 64 + qo + c * 4]);
                a = fmaf(q[c * 4 + 0], kv.x, a);
                a = fmaf(q[c * 4 + 1], kv.y, a);
                a = fmaf(q[c * 4 + 2], kv.z, a);
                a = fmaf(q[c * 4 + 3], kv.w, a);
            }
            a += __shfl_xor(a, 1);     // combine d-halves
            a *= scale;
            if (SHIFTED && rid_s[m] != myrid) a -= 100.f;
            s[m] = a;
        }
        float mx = s[0];
        #pragma unroll
        for (int m = 1; m < 64; ++m) mx = fmaxf(mx, s[m]);
        float sum = 0.f;
        #pragma unroll
        for (int m = 0; m < 64; ++m) { float e = __expf(s[m] - mx); s[m] = e; sum += e; }
        float inv = 1.0f / sum;
        float o[16];
        #pragma unroll
        for (int j = 0; j < 16; ++j) o[j] = 0.f;
        #pragma unroll
        for (int m = 0; m < 64; ++m) {
            float p = s[m];
            #pragma unroll
            for (int c = 0; c < 4; ++c) {
                float4 vv = *reinterpret_cast<const float4*>(&qs[m * QSW + 128 + qo + c * 4]);
                o[c * 4 + 0] = fmaf(p, vv.x, o[c * 4 + 0]);
                o[c * 4 + 1] = fmaf(p, vv.y, o[c * 4 + 1]);
                o[c * 4 + 2] = fmaf(p, vv.z, o[c * 4 + 2]);
                o[c * 4 + 3] = fmaf(p, vv.w, o[c * 4 + 3]);
            }
        }
        short8 sh[2], sl[2];
        #pragma unroll
        for (int j = 0; j < 16; ++j) {
            short hs, ls; split2(o[j] * inv, hs, ls);
            sh[j >> 3][j & 7] = hs; sl[j >> 3][j & 7] = ls;
        }
        *reinterpret_cast<short8*>(&hA[n * HAW + qo])             = sh[0];
        *reinterpret_cast<short8*>(&hA[n * HAW + qo + 8])         = sh[1];
        *reinterpret_cast<short8*>(&hA[HA_LO + n * HAW + qo])     = sl[0];
        *reinterpret_cast<short8*>(&hA[HA_LO + n * HAW + qo + 8]) = sl[1];
    }
    __syncthreads();

    // ---- D: proj (MFMA) + bias -> qs[.., 0:64)
    {
        short8 ah[4][2], al[4][2];
        #pragma unroll
        for (int mt = 0; mt < 4; ++mt)
            #pragma unroll
            for (int ks = 0; ks < 2; ++ks) {
                int off = (mt * 16 + lr) * HAW + ks * 32 + lg * 8;
                ah[mt][ks] = *reinterpret_cast<const short8*>(&hA[off]);
                al[mt][ks] = *reinterpret_cast<const short8*>(&hA[HA_LO + off]);
            }
        int c0 = wv * 16;
        short8 bh[2], bl[2];
        #pragma unroll
        for (int ks = 0; ks < 2; ++ks) {
            int fo = WOFF_PROJ + ((wv * 2 + ks) * 4 + lg) * 128 + lr * 8;
            bh[ks] = *reinterpret_cast<const short8*>(&whi[fo]);
            bl[ks] = *reinterpret_cast<const short8*>(&wlo[fo]);
        }
        f32x4 acc[4];
        #pragma unroll
        for (int mt = 0; mt < 4; ++mt) acc[mt] = (f32x4)(0.f);
        #pragma unroll
        for (int mt = 0; mt < 4; ++mt)
            #pragma unroll
            for (int ks = 0; ks < 2; ++ks) {
                MFMA3(acc[mt], ah[mt][ks], al[mt][ks], bh[ks], bl[ks]);
            }
        float pb = projb[c0 + lr];
        #pragma unroll
        for (int mt = 0; mt < 4; ++mt)
            #pragma unroll
            for (int j = 0; j < 4; ++j)
                qs[(mt * 16 + lg * 4 + j) * QSW + c0 + lr] = acc[mt][j] + pb;
    }
    __syncthreads();

    // ---- E: r2 = v + proj-out; RMSNorm(ln2) -> hA (bf16 split)
    {
        #pragma unroll
        for (int j = 0; j < 16; ++j) v[j] += qs[tok * QSW + seg * 16 + j];
        float ss = 0.f;
        #pragma unroll
        for (int j = 0; j < 16; ++j) ss = fmaf(v[j], v[j], ss);
        ss += __shfl_xor(ss, 1);
        ss += __shfl_xor(ss, 2);
        float r = rsqrtf(ss * (1.0f / 64.0f) + EPSV);
        short8 sh[2], sl[2];
        #pragma unroll
        for (int j = 0; j < 16; ++j) {
            float nv = v[j] * r * ln2[seg * 16 + j];
            short hs, ls; split2(nv, hs, ls);
            sh[j >> 3][j & 7] = hs; sl[j >> 3][j & 7] = ls;
        }
        *reinterpret_cast<short8*>(&hA[tok * HAW + seg * 16])         = sh[0];
        *reinterpret_cast<short8*>(&hA[tok * HAW + seg * 16 + 8])     = sh[1];
        *reinterpret_cast<short8*>(&hA[HA_LO + tok * HAW + seg * 16])     = sl[0];
        *reinterpret_cast<short8*>(&hA[HA_LO + tok * HAW + seg * 16 + 8]) = sl[1];
    }
    __syncthreads();

    // ---- F: mlp1 (MFMA) + bias + GELU -> ht (bf16 split, overlaying qs)
    {
        short8 ah[4][2], al[4][2];
        #pragma unroll
        for (int mt = 0; mt < 4; ++mt)
            #pragma unroll
            for (int ks = 0; ks < 2; ++ks) {
                int off = (mt * 16 + lr) * HAW + ks * 32 + lg * 8;
                ah[mt][ks] = *reinterpret_cast<const short8*>(&hA[off]);
                al[mt][ks] = *reinterpret_cast<const short8*>(&hA[HA_LO + off]);
            }
        #pragma unroll
        for (int nt = 0; nt < 2; ++nt) {
            int ct = wv * 2 + nt;
            int c0 = ct * 16;
            short8 bh[2], bl[2];
            #pragma unroll
            for (int ks = 0; ks < 2; ++ks) {
                int fo = WOFF_W1 + ((ct * 2 + ks) * 4 + lg) * 128 + lr * 8;
                bh[ks] = *reinterpret_cast<const short8*>(&whi[fo]);
                bl[ks] = *reinterpret_cast<const short8*>(&wlo[fo]);
            }
            f32x4 acc[4];
            #pragma unroll
            for (int mt = 0; mt < 4; ++mt) acc[mt] = (f32x4)(0.f);
            #pragma unroll
            for (int mt = 0; mt < 4; ++mt)
                #pragma unroll
                for (int ks = 0; ks < 2; ++ks) {
                    MFMA3(acc[mt], ah[mt][ks], al[mt][ks], bh[ks], bl[ks]);
                }
            float bb = b1[c0 + lr];
            #pragma unroll
            for (int mt = 0; mt < 4; ++mt)
                #pragma unroll
                for (int j = 0; j < 4; ++j) {
                    float u = acc[mt][j] + bb;
                    float g = 0.5f * u * (1.0f + erff(u * 0.70710678118654752f));
                    short hs, ls; split2(g, hs, ls);
                    int off = (mt * 16 + lg * 4 + j) * HTW + c0 + lr;
                    ht_hi[off] = (unsigned short)hs;
                    ht_lo[off] = (unsigned short)ls;
                }
        }
    }
    __syncthreads();

    // ---- G: mlp2 (MFMA, K=128) + bias -> hAf (fp32, overlaying hA)
    {
        int c0 = wv * 16;
        f32x4 acc[4];
        #pragma unroll
        for (int mt = 0; mt < 4; ++mt) acc[mt] = (f32x4)(0.f);
        #pragma unroll
        for (int ks = 0; ks < 4; ++ks) {
            int fo = WOFF_W2 + ((wv * 4 + ks) * 4 + lg) * 128 + lr * 8;
            short8 bh = *reinterpret_cast<const short8*>(&whi[fo]);
            short8 bl = *reinterpret_cast<const short8*>(&wlo[fo]);
            #pragma unroll
            for (int mt = 0; mt < 4; ++mt) {
                int off = (mt * 16 + lr) * HTW + ks * 32 + lg * 8;
                short8 ah = *reinterpret_cast<const short8*>(&ht_hi[off]);
                short8 al = *reinterpret_cast<const short8*>(&ht_lo[off]);
                MFMA3(acc[mt], ah, al, bh, bl);
            }
        }
        __syncthreads();   // hA (xt) fully consumed in phase F; safe to overwrite as fp32
        float bb = b2[c0 + lr];
        #pragma unroll
        for (int mt = 0; mt < 4; ++mt)
            #pragma unroll
            for (int j = 0; j < 4; ++j)
                hAf[(mt * 16 + lg * 4 + j) * HAW + c0 + lr] = acc[mt][j] + bb;
    }
    __syncthreads();

    // ---- H: h[lidx] = r2 + mlp-out
    {
        float* op = h + (size_t)lidx * 64 + seg * 16;
        #pragma unroll
        for (int c = 0; c < 4; ++c) {
            float4 o4;
            o4.x = v[c * 4 + 0] + hAf[tok * HAW + seg * 16 + c * 4 + 0];
            o4.y = v[c * 4 + 1] + hAf[tok * HAW + seg * 16 + c * 4 + 1];
            o4.z = v[c * 4 + 2] + hAf[tok * HAW + seg * 16 + c * 4 + 2];
            o4.w = v[c * 4 + 3] + hAf[tok * HAW + seg * 16 + c * 4 + 3];
            *reinterpret_cast<float4*>(op + c * 4) = o4;
        }
    }
}

// --------------------------------------------------------------- down + fold
// Block = (zg, yg): 64 tokens staged in LDS + both weight matrices; fully
// coalesced reads and 1KB/wave coalesced writes.
__global__ __launch_bounds__(256) void k_down(const float* __restrict__ h,
        const float* __restrict__ wp, const float* __restrict__ bp,
        const float* __restrict__ wc, const float* __restrict__ bc,
        float* __restrict__ out) {
    __shared__ float hs_[64][68];        // 64 tokens x 64 ch (pad 68 -> 16B-aligned rows)
    __shared__ float ws_[2][64][32];     // [pc][k][c]
    int b = blockIdx.x;                  // 2048 blocks: zg*64 + yg
    int zg = b >> 6, yg = b & 63;
    int tid = threadIdx.x;
    const float* hp = h + (size_t)(zg * 64 + yg) * 64 * 64;   // 4096 contiguous floats
    for (int i = tid; i < 1024; i += 256) {
        float4 t4 = reinterpret_cast<const float4*>(hp)[i];
        int tokx = i >> 4, c4 = (i & 15) * 4;
        *reinterpret_cast<float4*>(&hs_[tokx][c4]) = t4;
    }
    for (int i = tid; i < 512; i += 256) {
        reinterpret_cast<float4*>(&ws_[0][0][0])[i] = reinterpret_cast<const float4*>(wp)[i];
        reinterpret_cast<float4*>(&ws_[1][0][0])[i] = reinterpret_cast<const float4*>(wc)[i];
    }
    __syncthreads();
    int dc = tid >> 6, xg = tid & 63;
    float hv[64];
    #pragma unroll
    for (int j = 0; j < 16; ++j) {
        float4 t4 = *reinterpret_cast<const float4*>(&hs_[xg][j * 4]);
        hv[j * 4] = t4.x; hv[j * 4 + 1] = t4.y; hv[j * 4 + 2] = t4.z; hv[j * 4 + 3] = t4.w;
    }
    float4 acc[2][2];                    // [pc][ci], cb = dc + ci*4
    #pragma unroll
    for (int pc = 0; pc < 2; ++pc) {
        const float* bsel = pc ? bc : bp;
        #pragma unroll
        for (int ci = 0; ci < 2; ++ci)
            acc[pc][ci] = *reinterpret_cast<const float4*>(bsel + (dc + ci * 4) * 4);
    }
    #pragma unroll 8
    for (int k = 0; k < 64; ++k) {
        float a = hv[k];
        #pragma unroll
        for (int pc = 0; pc < 2; ++pc)
            #pragma unroll
            for (int ci = 0; ci < 2; ++ci) {
                float4 w4 = *reinterpret_cast<const float4*>(&ws_[pc][k][(dc + ci * 4) * 4]);
                acc[pc][ci].x = fmaf(a, w4.x, acc[pc][ci].x);
                acc[pc][ci].y = fmaf(a, w4.y, acc[pc][ci].y);
                acc[pc][ci].z = fmaf(a, w4.z, acc[pc][ci].z);
                acc[pc][ci].w = fmaf(a, w4.w, acc[pc][ci].w);
            }
    }
    #pragma unroll
    for (int pc = 0; pc < 2; ++pc)
        #pragma unroll
        for (int ci = 0; ci < 2; ++ci) {
            int cb = dc + ci * 4;
            int dz = cb >> 2, dy = cb & 3;
            float* op = out + (size_t)pc * (64u * 256u * 256u)
                      + ((size_t)(zg * 2 + dz) * 256 + (yg * 4 + dy)) * 256 + xg * 4;
            *reinterpret_cast<float4*>(op) = acc[pc][ci];
        }
}

// --------------------------------------------------------------------- launch
extern "C" void kernel_launch(void* const* d_in, const int* in_sizes, int n_in,
                              void* d_out, int out_size, void* d_ws, size_t ws_size,
                              hipStream_t stream) {
    const float* x        = (const float*)d_in[0];
    const float* up_w     = (const float*)d_in[1];
    const float* up_b     = (const float*)d_in[2];
    const float* ln1_w    = (const float*)d_in[3];
    const float* qkv_w    = (const float*)d_in[4];
    const float* proj_w   = (const float*)d_in[5];
    const float* proj_b   = (const float*)d_in[6];
    const float* ln2_w    = (const float*)d_in[7];
    const float* mlp_w1   = (const float*)d_in[8];
    const float* mlp_b1   = (const float*)d_in[9];
    const float* mlp_w2   = (const float*)d_in[10];
    const float* mlp_b2   = (const float*)d_in[11];
    const float* down_p_w = (const float*)d_in[12];
    const float* down_p_b = (const float*)d_in[13];
    const float* down_c_w = (const float*)d_in[14];
    const float* down_c_b = (const float*)d_in[15];
    float* out = (float*)d_out;
    float* h   = (float*)d_ws;                                   // 32 MB
    unsigned short* wsw = (unsigned short*)((char*)d_ws + (size_t)32 * 1024 * 1024);  // +2 MB

    k_wsplit<<<2048, 256, 0, stream>>>(qkv_w, proj_w, mlp_w1, mlp_w2, wsw);
    k_embed<<<2048, 256, 0, stream>>>(x, up_w, up_b, h);
    for (int i = 0; i < 16; ++i) {
        const unsigned short* whi = wsw + (size_t)i * LAYER_WSZ;
        const unsigned short* wlo = wsw + WTOT + (size_t)i * LAYER_WSZ;
        if (i & 1) k_layer<1><<<2048, 256, 0, stream>>>(h, ln1_w + i * 64, whi, wlo,
                proj_b + i * 64, ln2_w + i * 64, mlp_b1 + i * 128, mlp_b2 + i * 64);
        else       k_layer<0><<<2048, 256, 0, stream>>>(h, ln1_w + i * 64, whi, wlo,
                proj_b + i * 64, ln2_w + i * 64, mlp_b1 + i * 128, mlp_b2 + i * 64);
    }
    k_down<<<2048, 256, 0, stream>>>(h, down_p_w, down_p_b, down_c_w, down_c_b, out);
}